// Round 10
// baseline (1808.161 us; speedup 1.0000x reference)
//
#include <hip/hip_runtime.h>
#include <cstdint>
#include <cstddef>

#define BB   128
#define IN   1024
#define HID  4096
#define OUTN 1024
#define TSTEPS 100
#define KC   384   // OpenBLAS SGEMM_DEFAULT_Q — panel structure must be preserved exactly

// ---------------- tiled transpose: dst[c*R + r] = src[r*C + c] ----------------
__global__ __launch_bounds__(256) void ttrans_k(const float* __restrict__ src,
                                                float* __restrict__ dst,
                                                int R, int C) {
  __shared__ float tile[32][33];
  int tx = threadIdx.x & 31;
  int ty = threadIdx.x >> 5;            // 0..7
  int c0 = blockIdx.x * 32, r0 = blockIdx.y * 32;
  #pragma unroll
  for (int j = 0; j < 32; j += 8)
    tile[ty + j][tx] = src[(size_t)(r0 + ty + j) * C + (c0 + tx)];
  __syncthreads();
  #pragma unroll
  for (int j = 0; j < 32; j += 8)
    dst[(size_t)(c0 + ty + j) * R + (r0 + tx)] = tile[tx][ty + j];
}

// f32 LIF exactly mirroring the reference op order (no FMA contraction).
__device__ __forceinline__ unsigned char lif_f32(float I, float& v, float& r) {
  bool active = I > 0.0f;
  bool refrac = r > 0.0f;
  float vi = __fadd_rn(__fmul_rn(v, 0.95f), I);
  bool fired = active && !refrac && (vi >= 1.0f);
  float vn = !active ? v : ((refrac || fired) ? 0.0f : vi);
  float rn = !active ? r : (refrac ? (r - 1.0f) : (fired ? 2.0f : r));
  v = vn; r = rn;
  return fired ? (unsigned char)1 : (unsigned char)0;
}

// 8-deep batched gather over [ks,ke): 8 float2 loads in flight, ordered adds per
// column (ascending k) — bit-identical to the sequential gated scan.
#define GATHER8X2(SH)                                                            \
  {                                                                              \
    int k = ks;                                                                  \
    for (; k + 8 <= ke; k += 8) {                                                \
      unsigned o0 = ((unsigned)s_idx[k]     << SH) + cb;                         \
      unsigned o1 = ((unsigned)s_idx[k + 1] << SH) + cb;                         \
      unsigned o2 = ((unsigned)s_idx[k + 2] << SH) + cb;                         \
      unsigned o3 = ((unsigned)s_idx[k + 3] << SH) + cb;                         \
      unsigned o4 = ((unsigned)s_idx[k + 4] << SH) + cb;                         \
      unsigned o5 = ((unsigned)s_idx[k + 5] << SH) + cb;                         \
      unsigned o6 = ((unsigned)s_idx[k + 6] << SH) + cb;                         \
      unsigned o7 = ((unsigned)s_idx[k + 7] << SH) + cb;                         \
      float2 w0 = *reinterpret_cast<const float2*>(Wb + o0);                     \
      float2 w1 = *reinterpret_cast<const float2*>(Wb + o1);                     \
      float2 w2 = *reinterpret_cast<const float2*>(Wb + o2);                     \
      float2 w3 = *reinterpret_cast<const float2*>(Wb + o3);                     \
      float2 w4 = *reinterpret_cast<const float2*>(Wb + o4);                     \
      float2 w5 = *reinterpret_cast<const float2*>(Wb + o5);                     \
      float2 w6 = *reinterpret_cast<const float2*>(Wb + o6);                     \
      float2 w7 = *reinterpret_cast<const float2*>(Wb + o7);                     \
      a0 = __fadd_rn(a0, w0.x); a1 = __fadd_rn(a1, w0.y);                        \
      a0 = __fadd_rn(a0, w1.x); a1 = __fadd_rn(a1, w1.y);                        \
      a0 = __fadd_rn(a0, w2.x); a1 = __fadd_rn(a1, w2.y);                        \
      a0 = __fadd_rn(a0, w3.x); a1 = __fadd_rn(a1, w3.y);                        \
      a0 = __fadd_rn(a0, w4.x); a1 = __fadd_rn(a1, w4.y);                        \
      a0 = __fadd_rn(a0, w5.x); a1 = __fadd_rn(a1, w5.y);                        \
      a0 = __fadd_rn(a0, w6.x); a1 = __fadd_rn(a1, w6.y);                        \
      a0 = __fadd_rn(a0, w7.x); a1 = __fadd_rn(a1, w7.y);                        \
    }                                                                            \
    if (k + 4 <= ke) {                                                           \
      unsigned o0 = ((unsigned)s_idx[k]     << SH) + cb;                         \
      unsigned o1 = ((unsigned)s_idx[k + 1] << SH) + cb;                         \
      unsigned o2 = ((unsigned)s_idx[k + 2] << SH) + cb;                         \
      unsigned o3 = ((unsigned)s_idx[k + 3] << SH) + cb;                         \
      float2 w0 = *reinterpret_cast<const float2*>(Wb + o0);                     \
      float2 w1 = *reinterpret_cast<const float2*>(Wb + o1);                     \
      float2 w2 = *reinterpret_cast<const float2*>(Wb + o2);                     \
      float2 w3 = *reinterpret_cast<const float2*>(Wb + o3);                     \
      a0 = __fadd_rn(a0, w0.x); a1 = __fadd_rn(a1, w0.y);                        \
      a0 = __fadd_rn(a0, w1.x); a1 = __fadd_rn(a1, w1.y);                        \
      a0 = __fadd_rn(a0, w2.x); a1 = __fadd_rn(a1, w2.y);                        \
      a0 = __fadd_rn(a0, w3.x); a1 = __fadd_rn(a1, w3.y);                        \
      k += 4;                                                                    \
    }                                                                            \
    for (; k < ke; k++) {                                                        \
      unsigned oo = ((unsigned)s_idx[k] << SH) + cb;                             \
      float2 w = *reinterpret_cast<const float2*>(Wb + oo);                      \
      a0 = __fadd_rn(a0, w.x); a1 = __fadd_rn(a1, w.y);                          \
    }                                                                            \
  }

// ================= hidden role: fused encode + compaction + sparse panel sum =====
// Block covers 512 h-columns (bx in [0,8)); thread owns 2 cols (dwordx2 gather).
__device__ __forceinline__ void hidden_body(
    int bx, int b, int tid,
    const float* __restrict__ noise_t, const float* __restrict__ x,
    const float* __restrict__ rin_in, float* __restrict__ rin_out,
    unsigned char* __restrict__ in_spk,
    const float* __restrict__ W1T,
    float* __restrict__ v_h, float* __restrict__ r_h,
    unsigned char* __restrict__ hid_spk,
    unsigned short* s_idx, int* s_off, int* wsum) {
  // ---- fused encode: each thread owns k in [tid*4, tid*4+4) ----
  size_t ebase = (size_t)b * IN + (size_t)tid * 4;
  const float4 xv = *reinterpret_cast<const float4*>(x + ebase);
  const float4 nv = *reinterpret_cast<const float4*>(noise_t + ebase);
  const float4 rv = *reinterpret_cast<const float4*>(rin_in + ebase);
  float px[4] = {xv.x, xv.y, xv.z, xv.w};
  float pn[4] = {nv.x, nv.y, nv.z, nv.w};
  float pr[4] = {rv.x, rv.y, rv.z, rv.w};
  int f[4]; float rn[4];
  #pragma unroll
  for (int j = 0; j < 4; j++) {
    float p = __fmul_rn(px[j], 100.0f);
    p = fminf(fmaxf(p, 0.0f), 100.0f);
    p = __fmul_rn(p, 0.001f);
    bool s = pn[j] < p;                  // Bernoulli encode (strict <)
    bool refrac = pr[j] > 0.0f;
    bool fired = s && !refrac;           // input-layer v == 0 always (proven)
    rn[j] = !s ? pr[j] : (refrac ? (pr[j] - 1.0f) : 2.0f);
    f[j] = fired ? 1 : 0;
  }
  if (bx == 0) {                         // single owner commits state
    *reinterpret_cast<float4*>(rin_out + ebase) = make_float4(rn[0], rn[1], rn[2], rn[3]);
    uchar4 sp; sp.x = (unsigned char)f[0]; sp.y = (unsigned char)f[1];
    sp.z = (unsigned char)f[2]; sp.w = (unsigned char)f[3];
    *reinterpret_cast<uchar4*>(in_spk + ebase) = sp;
  }
  int cnt = f[0] + f[1] + f[2] + f[3];

  // ---- block exclusive scan ----
  int lane = tid & 63, wv = tid >> 6;
  int inc = cnt;
  #pragma unroll
  for (int d = 1; d < 64; d <<= 1) {
    int nn = __shfl_up(inc, d, 64);
    if (lane >= d) inc += nn;
  }
  if (lane == 63) wsum[wv] = inc;
  __syncthreads();
  int wbase = 0;
  #pragma unroll
  for (int w = 0; w < 4; w++) if (w < wv) wbase += wsum[w];
  int excl = wbase + inc - cnt;

  int o = excl, kb = tid * 4;
  if (f[0]) s_idx[o++] = (unsigned short)(kb);
  if (f[1]) s_idx[o++] = (unsigned short)(kb + 1);
  if (f[2]) s_idx[o++] = (unsigned short)(kb + 2);
  if (f[3]) s_idx[o++] = (unsigned short)(kb + 3);
  if (tid == 0)   s_off[0] = 0;
  if (tid == 96)  s_off[1] = excl;       // panel k=384
  if (tid == 192) s_off[2] = excl;       // panel k=768
  if (tid == 255) s_off[3] = excl + cnt;
  __syncthreads();

  // ---- gather: thread owns h0, h0+1; 32-bit offsets from uniform base ----
  int h0 = bx * 512 + tid * 2;
  const char* Wb = (const char*)W1T;
  unsigned cb = (unsigned)h0 << 2;
  float t0 = 0.0f, t1 = 0.0f;
  #pragma unroll
  for (int p = 0; p < 3; p++) {
    int ks = s_off[p], ke = s_off[p + 1];
    float a0 = 0.0f, a1 = 0.0f;
    GATHER8X2(14)                        // k*HID*4
    t0 = __fadd_rn(t0, a0); t1 = __fadd_rn(t1, a1);   // rn(0+P0)=P0 exact
  }
  size_t idx = (size_t)b * HID + h0;
  float2 vv = *reinterpret_cast<float2*>(v_h + idx);
  float2 rr = *reinterpret_cast<float2*>(r_h + idx);
  uchar2 sp;
  sp.x = lif_f32(t0, vv.x, rr.x);
  sp.y = lif_f32(t1, vv.y, rr.y);
  *reinterpret_cast<float2*>(v_h + idx) = vv;
  *reinterpret_cast<float2*>(r_h + idx) = rr;
  *reinterpret_cast<uchar2*>(hid_spk + idx) = sp;
}

// ================= out role: wave-split panels, 2 cols/thread, fold + LIF ========
// Block covers 128 output columns (bx in [0,8)); 11 KC panels split across the 4
// waves into LDS parts[11][128]; threads 0-127 fold one column each (ordered
// 11-add left-fold) + LIF — bit-identical.
__device__ __forceinline__ void out_body(
    int bx, int b, int tid,
    const unsigned char* __restrict__ hid_spk,
    const float* __restrict__ W2T,
    float* __restrict__ v_o, float* __restrict__ r_o,
    float* __restrict__ out_acc,
    unsigned short* s_idx, int* s_off, int* wsum, float* parts) {
  int lane = tid & 63, kg = tid >> 6;

  // each thread owns k in [tid*16, tid*16+16)
  uint4 u = *reinterpret_cast<const uint4*>(hid_spk + (size_t)b * HID + tid * 16);
  unsigned ww[4] = {u.x, u.y, u.z, u.w};
  int cnt = 0;
  #pragma unroll
  for (int j = 0; j < 16; j++) cnt += (ww[j >> 2] >> ((j & 3) * 8)) & 0xff;

  int inc = cnt;
  #pragma unroll
  for (int d = 1; d < 64; d <<= 1) {
    int nn = __shfl_up(inc, d, 64);
    if (lane >= d) inc += nn;
  }
  if (lane == 63) wsum[kg] = inc;
  __syncthreads();
  int wbase = 0;
  #pragma unroll
  for (int w = 0; w < 4; w++) if (w < kg) wbase += wsum[w];
  int excl = wbase + inc - cnt;

  int oo = excl, kb = tid * 16;
  #pragma unroll
  for (int j = 0; j < 16; j++) {
    if ((ww[j >> 2] >> ((j & 3) * 8)) & 0xff) s_idx[oo++] = (unsigned short)(kb + j);
  }
  // panel p starts at k = 384*p -> thread 24*p (384/16 == 24, exact)
  if ((tid % 24) == 0 && tid <= 240) s_off[tid / 24] = excl;
  if (tid == 255) s_off[11] = excl + cnt;
  __syncthreads();

  // ---- wave kg computes its panels for cols [bx*128 + lane*2 .. +2) ----
  const int pstart = (kg == 0) ? 0 : (kg == 1) ? 3 : (kg == 2) ? 6 : 9;
  const int pend   = (kg == 0) ? 3 : (kg == 1) ? 6 : (kg == 2) ? 9 : 11;
  int col0 = lane * 2;
  const char* Wb = (const char*)W2T;
  unsigned cb = ((unsigned)(bx * 128 + col0)) << 2;
  for (int p = pstart; p < pend; p++) {
    int ks = s_off[p], ke = s_off[p + 1];
    float a0 = 0.0f, a1 = 0.0f;
    GATHER8X2(12)                        // k*OUTN*4
    *reinterpret_cast<float2*>(parts + p * 128 + col0) = make_float2(a0, a1);
  }
  __syncthreads();

  // ---- threads 0-127 fold one column (ordered 11-add left-fold) + LIF ----
  if (tid < 128) {
    float total = 0.0f;
    #pragma unroll
    for (int p = 0; p < 11; p++) total = __fadd_rn(total, parts[p * 128 + tid]);
    int o = bx * 128 + tid;
    size_t idx = (size_t)b * OUTN + o;
    float v = v_o[idx], r = r_o[idx];
    unsigned char fired = lif_f32(total, v, r);
    v_o[idx] = v; r_o[idx] = r;
    if (fired) out_acc[idx] = __fadd_rn(out_acc[idx], 1.0f);  // exact int count
  }
}

// ---------------- standalone boundary kernels ----------------
__global__ __launch_bounds__(256) void hidden_k(
    const float* __restrict__ noise_t, const float* __restrict__ x,
    const float* __restrict__ rin_in, float* __restrict__ rin_out,
    unsigned char* __restrict__ in_spk,
    const float* __restrict__ W1T,
    float* __restrict__ v_h, float* __restrict__ r_h,
    unsigned char* __restrict__ hid_spk) {
  __shared__ unsigned short s_idx[IN];
  __shared__ int s_off[4];
  __shared__ int wsum[4];
  hidden_body(blockIdx.x, blockIdx.y, threadIdx.x, noise_t, x, rin_in, rin_out,
              in_spk, W1T, v_h, r_h, hid_spk, s_idx, s_off, wsum);
}

__global__ __launch_bounds__(256) void out_k(
    const unsigned char* __restrict__ hid_spk, const float* __restrict__ W2T,
    float* __restrict__ v_o, float* __restrict__ r_o, float* __restrict__ out_acc) {
  __shared__ unsigned short s_idx[HID];
  __shared__ int s_off[12];
  __shared__ int wsum[4];
  __shared__ float parts[11 * 128];
  out_body(blockIdx.x, blockIdx.y, threadIdx.x, hid_spk, W2T, v_o, r_o, out_acc,
           s_idx, s_off, wsum, parts);
}

// ---------------- merged step: out(t-1) || hidden(t) in one launch ---------------
// grid (16, BB): x<8 hidden (512 cols), x>=8 out (128 cols). XCD = x%8 -> every
// XCD serves one 2MB W1T slice + one 2MB W2T slice = exactly its 4MB L2; both
// roles on all XCDs; 8 blocks/CU.
__global__ __launch_bounds__(256) void step_k(
    const float* __restrict__ noise_t, const float* __restrict__ x,
    const float* __restrict__ rin_in, float* __restrict__ rin_out,
    unsigned char* __restrict__ in_spk,
    const float* __restrict__ W1T,
    float* __restrict__ v_h, float* __restrict__ r_h,
    unsigned char* __restrict__ hid_spk_w,
    const unsigned char* __restrict__ hid_spk_r,
    const float* __restrict__ W2T,
    float* __restrict__ v_o, float* __restrict__ r_o, float* __restrict__ out_acc) {
  __shared__ __align__(16) unsigned char smem[13952];
  int b = blockIdx.y;
  if (blockIdx.x < 8) {
    unsigned short* s_idx = (unsigned short*)smem;              // 2048 B
    int* s_off = (int*)(smem + 2048);
    int* wsum  = (int*)(smem + 2064);
    hidden_body(blockIdx.x, b, threadIdx.x, noise_t, x, rin_in, rin_out,
                in_spk, W1T, v_h, r_h, hid_spk_w, s_idx, s_off, wsum);
  } else {
    unsigned short* s_idx = (unsigned short*)smem;              // 8192 B
    int* s_off = (int*)(smem + 8192);
    int* wsum  = (int*)(smem + 8240);
    float* parts = (float*)(smem + 8256);                        // 5632 B
    out_body(blockIdx.x - 8, b, threadIdx.x, hid_spk_r, W2T, v_o, r_o, out_acc,
             s_idx, s_off, wsum, parts);
  }
}

// ---------------- STDP: stats1 (counts + flags) then apply2 (trace + W) ----------
#define NWSTAT ((IN + HID) / 4)   // 1280 u32 words
__global__ __launch_bounds__(256) void stats1_k(
    const unsigned char* __restrict__ in_spk, const unsigned char* __restrict__ hid_spk,
    unsigned* __restrict__ pcnt, int* __restrict__ flags) {
  int w = blockIdx.x * 256 + threadIdx.x;   // word index in [0, NWSTAT)
  int r0 = blockIdx.y * 8;                  // 16 chunks x 8 rows
  int lane = threadIdx.x & 63;
  unsigned s = 0;
  if (w < IN / 4) {
    const unsigned* p = (const unsigned*)in_spk;
    #pragma unroll
    for (int b = 0; b < 8; b++) s += p[(size_t)(r0 + b) * (IN / 4) + w];
    atomicAdd(pcnt + w, s);
    unsigned long long any = __ballot(s > 0);
    if (any && lane == 0) atomicOr(flags + 0, 1);
  } else {
    const unsigned* p = (const unsigned*)hid_spk;
    int w2 = w - IN / 4;
    #pragma unroll
    for (int b = 0; b < 8; b++) s += p[(size_t)(r0 + b) * (HID / 4) + w2];
    atomicAdd(pcnt + w, s);
    unsigned long long any = __ballot(s > 0);
    if (any && lane == 0) atomicOr(flags + 1, 1);
  }
}

// apply2: pm = cnt * 2^-7 (== __fdiv_rn(cnt,128), pow2 exact). tp/tn ping-pong
// (read buffer never written -> race-free); W1T update gated by 'both' flags.
__global__ __launch_bounds__(256) void apply2_k(
    float* __restrict__ W1T,
    const unsigned* __restrict__ pcnt,
    const float* __restrict__ tp_in, float* __restrict__ tp_out,
    const float* __restrict__ tn_in, float* __restrict__ tn_out,
    const int* __restrict__ flags) {
  size_t idx = (size_t)blockIdx.x * 256 + threadIdx.x;  // i*HID + h layout
  int i = (int)(idx >> 12);
  int h = (int)(idx & 4095);
  int cnt_i = (int)((pcnt[i >> 2] >> ((i & 3) * 8)) & 0xff);
  int ch = IN + h;
  int cnt_h = (int)((pcnt[ch >> 2] >> ((ch & 3) * 8)) & 0xff);
  float pm_i = __fmul_rn((float)cnt_i, 0.0078125f);     // == fdiv_rn(cnt,128)
  float pm_h = __fmul_rn((float)cnt_h, 0.0078125f);
  float tpn = __fadd_rn(__fmul_rn(0.9f, tp_in[i]), pm_i);
  float tnn = __fadd_rn(__fmul_rn(0.9f, tn_in[h]), pm_h);
  if (h == 0) tp_out[i] = tpn;           // one committer per i
  if (i == 0) tn_out[h] = tnn;           // one committer per h
  if (!(flags[0] && flags[1])) return;   // 'both' gate (W only)
  float a  = __fmul_rn(tpn, pm_h);       // tp_n * post_m
  float b2 = __fmul_rn(pm_i, tnn);       // pre_m * tn_n
  float d  = __fmul_rn(0.001f, __fsub_rn(a, b2));
  float w  = __fadd_rn(W1T[idx], d);
  w = fminf(fmaxf(w, -1.0f), 1.0f);      // jnp.clip: max then min
  W1T[idx] = w;
}

__global__ __launch_bounds__(256) void scale_k(const float* __restrict__ acc,
                                               float* __restrict__ out) {
  int j = blockIdx.x * 256 + threadIdx.x;
  out[j] = __fdiv_rn(acc[j], 100.0f);
}

// ---------------- host launcher ----------------
extern "C" void kernel_launch(void* const* d_in, const int* in_sizes, int n_in,
                              void* d_out, int out_size, void* d_ws, size_t ws_size,
                              hipStream_t stream) {
  (void)in_sizes; (void)n_in; (void)out_size; (void)ws_size;
  const float* x     = (const float*)d_in[0];
  const float* W1    = (const float*)d_in[1];
  const float* W2    = (const float*)d_in[2];
  const float* noise = (const float*)d_in[3];

  char* ws = (char*)d_ws;
  size_t off = 0;
  auto alloc = [&](size_t bytes) -> char* {
    char* p = ws + off;
    off += (bytes + 255) & ~(size_t)255;
    return p;
  };
  float* W1T   = (float*)alloc((size_t)IN * HID * 4);     // 16 MB working copy (i-major)
  float* W2T   = (float*)alloc((size_t)HID * OUTN * 4);   // 16 MB (h-major)
  float* v_h   = (float*)alloc((size_t)BB * HID * 4);
  float* r_h   = (float*)alloc((size_t)BB * HID * 4);
  float* v_o   = (float*)alloc((size_t)BB * OUTN * 4);
  float* r_o   = (float*)alloc((size_t)BB * OUTN * 4);
  float* rinA  = (float*)alloc((size_t)BB * IN * 4);      // ping-pong refractory state
  float* rinB  = (float*)alloc((size_t)BB * IN * 4);
  float* acc   = (float*)alloc((size_t)BB * OUTN * 4);
  float* tpA   = (float*)alloc((size_t)IN * 4);           // ping-pong traces
  float* tpB   = (float*)alloc((size_t)IN * 4);
  float* tnA   = (float*)alloc((size_t)HID * 4);
  float* tnB   = (float*)alloc((size_t)HID * 4);
  unsigned char* in_spk   = (unsigned char*)alloc((size_t)BB * IN);
  unsigned char* hid_spkA = (unsigned char*)alloc((size_t)BB * HID);  // ping-pong
  unsigned char* hid_spkB = (unsigned char*)alloc((size_t)BB * HID);
  unsigned* pcnt = (unsigned*)alloc((size_t)10 * NWSTAT * 4);  // per-STDP-step slots
  int* flags   = (int*)alloc(2 * 10 * sizeof(int));            // per-STDP-step slots

  // zero all state (ws is poisoned before every call)
  hipMemsetAsync(v_h, 0, (size_t)BB * HID * 4, stream);
  hipMemsetAsync(r_h, 0, (size_t)BB * HID * 4, stream);
  hipMemsetAsync(v_o, 0, (size_t)BB * OUTN * 4, stream);
  hipMemsetAsync(r_o, 0, (size_t)BB * OUTN * 4, stream);
  hipMemsetAsync(rinA, 0, (size_t)BB * IN * 4, stream);
  hipMemsetAsync(acc, 0, (size_t)BB * OUTN * 4, stream);
  hipMemsetAsync(tpA, 0, (size_t)IN * 4, stream);
  hipMemsetAsync(tnA, 0, (size_t)HID * 4, stream);
  hipMemsetAsync(pcnt, 0, (size_t)10 * NWSTAT * 4, stream);
  hipMemsetAsync(flags, 0, 2 * 10 * sizeof(int), stream);

  // W1 (HID x IN) -> W1T (IN x HID); W2 (OUTN x HID) -> W2T (HID x OUTN). Tiled.
  ttrans_k<<<dim3(IN / 32, HID / 32), 256, 0, stream>>>(W1, W1T, HID, IN);
  ttrans_k<<<dim3(HID / 32, OUTN / 32), 256, 0, stream>>>(W2, W2T, OUTN, HID);

  float* rin_in = rinA;
  float* rin_out = rinB;
  float* tp_in = tpA; float* tp_out = tpB;
  float* tn_in = tnA; float* tn_out = tnB;

  // t = 0: hidden only
  hidden_k<<<dim3(8, BB), 256, 0, stream>>>(noise, x, rin_in, rin_out, in_spk,
                                            W1T, v_h, r_h, hid_spkA);
  {
    unsigned* pc = pcnt;  int* fl = flags;
    stats1_k<<<dim3(NWSTAT / 256, 16), 256, 0, stream>>>(in_spk, hid_spkA, pc, fl);
    apply2_k<<<(IN * HID) / 256, 256, 0, stream>>>(W1T, pc, tp_in, tp_out,
                                                   tn_in, tn_out, fl);
    float* t1 = tp_in; tp_in = tp_out; tp_out = t1;
    float* t2 = tn_in; tn_in = tn_out; tn_out = t2;
  }
  { float* tmpp = rin_in; rin_in = rin_out; rin_out = tmpp; }

  // t = 1..99: merged out(t-1) || hidden(t)
  for (int t = 1; t < TSTEPS; t++) {
    const float* nz = noise + (size_t)t * BB * IN;
    unsigned char* hs_w = (t & 1) ? hid_spkB : hid_spkA;
    unsigned char* hs_r = (t & 1) ? hid_spkA : hid_spkB;
    step_k<<<dim3(16, BB), 256, 0, stream>>>(nz, x, rin_in, rin_out, in_spk,
                                             W1T, v_h, r_h, hs_w, hs_r,
                                             W2T, v_o, r_o, acc);
    if (t % 10 == 0) {
      unsigned* pc = pcnt + (size_t)NWSTAT * (t / 10);
      int* fl = flags + 2 * (t / 10);
      stats1_k<<<dim3(NWSTAT / 256, 16), 256, 0, stream>>>(in_spk, hs_w, pc, fl);
      apply2_k<<<(IN * HID) / 256, 256, 0, stream>>>(W1T, pc, tp_in, tp_out,
                                                     tn_in, tn_out, fl);
      float* t1 = tp_in; tp_in = tp_out; tp_out = t1;
      float* t2 = tn_in; tn_in = tn_out; tn_out = t2;
    }
    float* tmpp = rin_in; rin_in = rin_out; rin_out = tmpp;
  }

  // final: out(99)
  unsigned char* hs_last = ((TSTEPS - 1) & 1) ? hid_spkB : hid_spkA;
  out_k<<<dim3(8, BB), 256, 0, stream>>>(hs_last, W2T, v_o, r_o, acc);

  scale_k<<<(BB * OUTN) / 256, 256, 0, stream>>>(acc, (float*)d_out);
}

// Round 11
// 1486.748 us; speedup vs baseline: 1.2162x; 1.2162x over previous
//
#include <hip/hip_runtime.h>
#include <cstdint>
#include <cstddef>

#define BB   128
#define IN   1024
#define HID  4096
#define OUTN 1024
#define TSTEPS 100
#define KC   384   // OpenBLAS SGEMM_DEFAULT_Q — panel structure must be preserved exactly

// ---------------- tiled transpose: dst[c*R + r] = src[r*C + c] ----------------
__global__ __launch_bounds__(256) void ttrans_k(const float* __restrict__ src,
                                                float* __restrict__ dst,
                                                int R, int C) {
  __shared__ float tile[32][33];
  int tx = threadIdx.x & 31;
  int ty = threadIdx.x >> 5;            // 0..7
  int c0 = blockIdx.x * 32, r0 = blockIdx.y * 32;
  #pragma unroll
  for (int j = 0; j < 32; j += 8)
    tile[ty + j][tx] = src[(size_t)(r0 + ty + j) * C + (c0 + tx)];
  __syncthreads();
  #pragma unroll
  for (int j = 0; j < 32; j += 8)
    dst[(size_t)(c0 + ty + j) * R + (r0 + tx)] = tile[tx][ty + j];
}

// f32 LIF exactly mirroring the reference op order (no FMA contraction).
__device__ __forceinline__ unsigned char lif_f32(float I, float& v, float& r) {
  bool active = I > 0.0f;
  bool refrac = r > 0.0f;
  float vi = __fadd_rn(__fmul_rn(v, 0.95f), I);
  bool fired = active && !refrac && (vi >= 1.0f);
  float vn = !active ? v : ((refrac || fired) ? 0.0f : vi);
  float rn = !active ? r : (refrac ? (r - 1.0f) : (fired ? 2.0f : r));
  v = vn; r = rn;
  return fired ? (unsigned char)1 : (unsigned char)0;
}

// 8-deep batched gather over [ks,ke): float4 loads (16B/lane — request-count
// optimal, proven R9), ordered adds per column (ascending k) — bit-identical.
#define GATHER8(SH)                                                              \
  {                                                                              \
    int k = ks;                                                                  \
    for (; k + 8 <= ke; k += 8) {                                                \
      unsigned o0 = ((unsigned)s_idx[k]     << SH) + cb;                         \
      unsigned o1 = ((unsigned)s_idx[k + 1] << SH) + cb;                         \
      unsigned o2 = ((unsigned)s_idx[k + 2] << SH) + cb;                         \
      unsigned o3 = ((unsigned)s_idx[k + 3] << SH) + cb;                         \
      unsigned o4 = ((unsigned)s_idx[k + 4] << SH) + cb;                         \
      unsigned o5 = ((unsigned)s_idx[k + 5] << SH) + cb;                         \
      unsigned o6 = ((unsigned)s_idx[k + 6] << SH) + cb;                         \
      unsigned o7 = ((unsigned)s_idx[k + 7] << SH) + cb;                         \
      float4 w0 = *reinterpret_cast<const float4*>(Wb + o0);                     \
      float4 w1 = *reinterpret_cast<const float4*>(Wb + o1);                     \
      float4 w2 = *reinterpret_cast<const float4*>(Wb + o2);                     \
      float4 w3 = *reinterpret_cast<const float4*>(Wb + o3);                     \
      float4 w4 = *reinterpret_cast<const float4*>(Wb + o4);                     \
      float4 w5 = *reinterpret_cast<const float4*>(Wb + o5);                     \
      float4 w6 = *reinterpret_cast<const float4*>(Wb + o6);                     \
      float4 w7 = *reinterpret_cast<const float4*>(Wb + o7);                     \
      a0 = __fadd_rn(a0, w0.x); a1 = __fadd_rn(a1, w0.y);                        \
      a2 = __fadd_rn(a2, w0.z); a3 = __fadd_rn(a3, w0.w);                        \
      a0 = __fadd_rn(a0, w1.x); a1 = __fadd_rn(a1, w1.y);                        \
      a2 = __fadd_rn(a2, w1.z); a3 = __fadd_rn(a3, w1.w);                        \
      a0 = __fadd_rn(a0, w2.x); a1 = __fadd_rn(a1, w2.y);                        \
      a2 = __fadd_rn(a2, w2.z); a3 = __fadd_rn(a3, w2.w);                        \
      a0 = __fadd_rn(a0, w3.x); a1 = __fadd_rn(a1, w3.y);                        \
      a2 = __fadd_rn(a2, w3.z); a3 = __fadd_rn(a3, w3.w);                        \
      a0 = __fadd_rn(a0, w4.x); a1 = __fadd_rn(a1, w4.y);                        \
      a2 = __fadd_rn(a2, w4.z); a3 = __fadd_rn(a3, w4.w);                        \
      a0 = __fadd_rn(a0, w5.x); a1 = __fadd_rn(a1, w5.y);                        \
      a2 = __fadd_rn(a2, w5.z); a3 = __fadd_rn(a3, w5.w);                        \
      a0 = __fadd_rn(a0, w6.x); a1 = __fadd_rn(a1, w6.y);                        \
      a2 = __fadd_rn(a2, w6.z); a3 = __fadd_rn(a3, w6.w);                        \
      a0 = __fadd_rn(a0, w7.x); a1 = __fadd_rn(a1, w7.y);                        \
      a2 = __fadd_rn(a2, w7.z); a3 = __fadd_rn(a3, w7.w);                        \
    }                                                                            \
    if (k + 4 <= ke) {                                                           \
      unsigned o0 = ((unsigned)s_idx[k]     << SH) + cb;                         \
      unsigned o1 = ((unsigned)s_idx[k + 1] << SH) + cb;                         \
      unsigned o2 = ((unsigned)s_idx[k + 2] << SH) + cb;                         \
      unsigned o3 = ((unsigned)s_idx[k + 3] << SH) + cb;                         \
      float4 w0 = *reinterpret_cast<const float4*>(Wb + o0);                     \
      float4 w1 = *reinterpret_cast<const float4*>(Wb + o1);                     \
      float4 w2 = *reinterpret_cast<const float4*>(Wb + o2);                     \
      float4 w3 = *reinterpret_cast<const float4*>(Wb + o3);                     \
      a0 = __fadd_rn(a0, w0.x); a1 = __fadd_rn(a1, w0.y);                        \
      a2 = __fadd_rn(a2, w0.z); a3 = __fadd_rn(a3, w0.w);                        \
      a0 = __fadd_rn(a0, w1.x); a1 = __fadd_rn(a1, w1.y);                        \
      a2 = __fadd_rn(a2, w1.z); a3 = __fadd_rn(a3, w1.w);                        \
      a0 = __fadd_rn(a0, w2.x); a1 = __fadd_rn(a1, w2.y);                        \
      a2 = __fadd_rn(a2, w2.z); a3 = __fadd_rn(a3, w2.w);                        \
      a0 = __fadd_rn(a0, w3.x); a1 = __fadd_rn(a1, w3.y);                        \
      a2 = __fadd_rn(a2, w3.z); a3 = __fadd_rn(a3, w3.w);                        \
      k += 4;                                                                    \
    }                                                                            \
    for (; k < ke; k++) {                                                        \
      unsigned oo = ((unsigned)s_idx[k] << SH) + cb;                             \
      float4 w = *reinterpret_cast<const float4*>(Wb + oo);                      \
      a0 = __fadd_rn(a0, w.x); a1 = __fadd_rn(a1, w.y);                          \
      a2 = __fadd_rn(a2, w.z); a3 = __fadd_rn(a3, w.w);                          \
    }                                                                            \
  }

// ---------------- encode helper (one thread <-> 4 input elems) ----------------
__device__ __forceinline__ int encode4(
    int bx, int b, int tid,
    const float* __restrict__ noise_t, const float* __restrict__ x,
    const float* __restrict__ rin_in, float* __restrict__ rin_out,
    unsigned char* __restrict__ in_spk, int f[4]) {
  size_t ebase = (size_t)b * IN + (size_t)tid * 4;
  const float4 xv = *reinterpret_cast<const float4*>(x + ebase);
  const float4 nv = *reinterpret_cast<const float4*>(noise_t + ebase);
  const float4 rv = *reinterpret_cast<const float4*>(rin_in + ebase);
  float px[4] = {xv.x, xv.y, xv.z, xv.w};
  float pn[4] = {nv.x, nv.y, nv.z, nv.w};
  float pr[4] = {rv.x, rv.y, rv.z, rv.w};
  float rn[4];
  #pragma unroll
  for (int j = 0; j < 4; j++) {
    float p = __fmul_rn(px[j], 100.0f);
    p = fminf(fmaxf(p, 0.0f), 100.0f);
    p = __fmul_rn(p, 0.001f);
    bool s = pn[j] < p;                  // Bernoulli encode (strict <)
    bool refrac = pr[j] > 0.0f;
    bool fired = s && !refrac;           // input-layer v == 0 always (proven)
    rn[j] = !s ? pr[j] : (refrac ? (pr[j] - 1.0f) : 2.0f);
    f[j] = fired ? 1 : 0;
  }
  if (bx == 0) {                         // single owner commits state
    *reinterpret_cast<float4*>(rin_out + ebase) = make_float4(rn[0], rn[1], rn[2], rn[3]);
    uchar4 sp; sp.x = (unsigned char)f[0]; sp.y = (unsigned char)f[1];
    sp.z = (unsigned char)f[2]; sp.w = (unsigned char)f[3];
    *reinterpret_cast<uchar4*>(in_spk + ebase) = sp;
  }
  return f[0] + f[1] + f[2] + f[3];
}

// ================= boundary-kernel bodies (256 threads, round-8 proven) =========
__device__ __forceinline__ void hidden_body(
    int bx, int b, int tid,
    const float* __restrict__ noise_t, const float* __restrict__ x,
    const float* __restrict__ rin_in, float* __restrict__ rin_out,
    unsigned char* __restrict__ in_spk,
    const float* __restrict__ W1T,
    float* __restrict__ v_h, float* __restrict__ r_h,
    unsigned char* __restrict__ hid_spk,
    unsigned short* s_idx, int* s_off, int* wsum) {
  int f[4];
  int cnt = encode4(bx, b, tid, noise_t, x, rin_in, rin_out, in_spk, f);

  int lane = tid & 63, wv = tid >> 6;
  int inc = cnt;
  #pragma unroll
  for (int d = 1; d < 64; d <<= 1) {
    int nn = __shfl_up(inc, d, 64);
    if (lane >= d) inc += nn;
  }
  if (lane == 63) wsum[wv] = inc;
  __syncthreads();
  int wbase = 0;
  #pragma unroll
  for (int w = 0; w < 4; w++) if (w < wv) wbase += wsum[w];
  int excl = wbase + inc - cnt;

  int o = excl, kb = tid * 4;
  if (f[0]) s_idx[o++] = (unsigned short)(kb);
  if (f[1]) s_idx[o++] = (unsigned short)(kb + 1);
  if (f[2]) s_idx[o++] = (unsigned short)(kb + 2);
  if (f[3]) s_idx[o++] = (unsigned short)(kb + 3);
  if (tid == 0)   s_off[0] = 0;
  if (tid == 96)  s_off[1] = excl;       // panel k=384
  if (tid == 192) s_off[2] = excl;       // panel k=768
  if (tid == 255) s_off[3] = excl + cnt;
  __syncthreads();

  int h0 = bx * 1024 + tid * 4;
  const char* Wb = (const char*)W1T;
  unsigned cb = (unsigned)h0 << 2;
  float t0 = 0.0f, t1 = 0.0f, t2 = 0.0f, t3 = 0.0f;
  #pragma unroll
  for (int p = 0; p < 3; p++) {
    int ks = s_off[p], ke = s_off[p + 1];
    float a0 = 0.0f, a1 = 0.0f, a2 = 0.0f, a3 = 0.0f;
    GATHER8(14)                          // k*HID*4
    t0 = __fadd_rn(t0, a0); t1 = __fadd_rn(t1, a1);   // rn(0+P0)=P0 exact
    t2 = __fadd_rn(t2, a2); t3 = __fadd_rn(t3, a3);
  }
  size_t idx = (size_t)b * HID + h0;
  float4 vv = *reinterpret_cast<float4*>(v_h + idx);
  float4 rr = *reinterpret_cast<float4*>(r_h + idx);
  uchar4 sp;
  sp.x = lif_f32(t0, vv.x, rr.x);
  sp.y = lif_f32(t1, vv.y, rr.y);
  sp.z = lif_f32(t2, vv.z, rr.z);
  sp.w = lif_f32(t3, vv.w, rr.w);
  *reinterpret_cast<float4*>(v_h + idx) = vv;
  *reinterpret_cast<float4*>(r_h + idx) = rr;
  *reinterpret_cast<uchar4*>(hid_spk + idx) = sp;
}

__device__ __forceinline__ void out_body(
    int bx, int b, int tid,
    const unsigned char* __restrict__ hid_spk,
    const float* __restrict__ W2T,
    float* __restrict__ v_o, float* __restrict__ r_o,
    float* __restrict__ out_acc,
    unsigned short* s_idx, int* s_off, int* wsum, float* parts) {
  int lane = tid & 63, kg = tid >> 6;

  uint4 u = *reinterpret_cast<const uint4*>(hid_spk + (size_t)b * HID + tid * 16);
  unsigned ww[4] = {u.x, u.y, u.z, u.w};
  int cnt = 0;
  #pragma unroll
  for (int j = 0; j < 16; j++) cnt += (ww[j >> 2] >> ((j & 3) * 8)) & 0xff;

  int inc = cnt;
  #pragma unroll
  for (int d = 1; d < 64; d <<= 1) {
    int nn = __shfl_up(inc, d, 64);
    if (lane >= d) inc += nn;
  }
  if (lane == 63) wsum[kg] = inc;
  __syncthreads();
  int wbase = 0;
  #pragma unroll
  for (int w = 0; w < 4; w++) if (w < kg) wbase += wsum[w];
  int excl = wbase + inc - cnt;

  int oo = excl, kb = tid * 16;
  #pragma unroll
  for (int j = 0; j < 16; j++) {
    if ((ww[j >> 2] >> ((j & 3) * 8)) & 0xff) s_idx[oo++] = (unsigned short)(kb + j);
  }
  if ((tid % 24) == 0 && tid <= 240) s_off[tid / 24] = excl;
  if (tid == 255) s_off[11] = excl + cnt;
  __syncthreads();

  const int pstart = (kg == 0) ? 0 : (kg == 1) ? 3 : (kg == 2) ? 6 : 9;
  const int pend   = (kg == 0) ? 3 : (kg == 1) ? 6 : (kg == 2) ? 9 : 11;
  int col0 = lane * 4;
  const char* Wb = (const char*)W2T;
  unsigned cb = ((unsigned)(bx * 256 + col0)) << 2;
  for (int p = pstart; p < pend; p++) {
    int ks = s_off[p], ke = s_off[p + 1];
    float a0 = 0.0f, a1 = 0.0f, a2 = 0.0f, a3 = 0.0f;
    GATHER8(12)                          // k*OUTN*4
    *reinterpret_cast<float4*>(parts + p * 256 + col0) = make_float4(a0, a1, a2, a3);
  }
  __syncthreads();

  float total = 0.0f;
  #pragma unroll
  for (int p = 0; p < 11; p++) total = __fadd_rn(total, parts[p * 256 + tid]);
  int o = bx * 256 + tid;
  size_t idx = (size_t)b * OUTN + o;
  float v = v_o[idx], r = r_o[idx];
  unsigned char fired = lif_f32(total, v, r);
  v_o[idx] = v; r_o[idx] = r;
  if (fired) out_acc[idx] = __fadd_rn(out_acc[idx], 1.0f);  // exact int count
}

__global__ __launch_bounds__(256) void hidden_k(
    const float* __restrict__ noise_t, const float* __restrict__ x,
    const float* __restrict__ rin_in, float* __restrict__ rin_out,
    unsigned char* __restrict__ in_spk,
    const float* __restrict__ W1T,
    float* __restrict__ v_h, float* __restrict__ r_h,
    unsigned char* __restrict__ hid_spk) {
  __shared__ unsigned short s_idx[IN];
  __shared__ int s_off[4];
  __shared__ int wsum[4];
  hidden_body(blockIdx.x, blockIdx.y, threadIdx.x, noise_t, x, rin_in, rin_out,
              in_spk, W1T, v_h, r_h, hid_spk, s_idx, s_off, wsum);
}

__global__ __launch_bounds__(256) void out_k(
    const unsigned char* __restrict__ hid_spk, const float* __restrict__ W2T,
    float* __restrict__ v_o, float* __restrict__ r_o, float* __restrict__ out_acc) {
  __shared__ unsigned short s_idx[HID];
  __shared__ int s_off[12];
  __shared__ int wsum[4];
  __shared__ float parts[11 * 256];
  out_body(blockIdx.x, blockIdx.y, threadIdx.x, hid_spk, W2T, v_o, r_o, out_acc,
           s_idx, s_off, wsum, parts);
}

// ---------------- merged step, 512 threads: 2x resident waves -------------------
// Panel-split across 8 waves at CONSTANT float4 width. Hidden: waves 0-3 compute
// the ordered prefix sA = fadd(fadd(0,P0),P1); waves 4-7 compute P2; fold
// fadd(sA,P2) — identical left-fold. Out: 11 panels over 8 waves; the single
// ordered 11-add fold is unchanged. Grid (8,BB) x 512 = 32 waves/CU (was 16).
__global__ __launch_bounds__(512) void step_k(
    const float* __restrict__ noise_t, const float* __restrict__ x,
    const float* __restrict__ rin_in, float* __restrict__ rin_out,
    unsigned char* __restrict__ in_spk,
    const float* __restrict__ W1T,
    float* __restrict__ v_h, float* __restrict__ r_h,
    unsigned char* __restrict__ hid_spk_w,
    const unsigned char* __restrict__ hid_spk_r,
    const float* __restrict__ W2T,
    float* __restrict__ v_o, float* __restrict__ r_o, float* __restrict__ out_acc) {
  __shared__ __align__(16) unsigned char smem[19520];
  int tid = threadIdx.x;
  int b = blockIdx.y;
  int lane = tid & 63, wv = tid >> 6;

  if (blockIdx.x < 4) {
    // ---- hidden role: block covers 1024 cols; wave-group panel split ----
    unsigned short* s_idx = (unsigned short*)smem;              // 2048 B
    int* s_off = (int*)(smem + 2048);                            // 16 B
    int* wsum  = (int*)(smem + 2064);                            // 16 B
    float* sA  = (float*)(smem + 2080);                          // 4096 B
    float* p2  = (float*)(smem + 6176);                          // 4096 B
    int bx = blockIdx.x;
    int f[4]; int cnt = 0, inc = 0;
    if (tid < 256) {
      cnt = encode4(bx, b, tid, noise_t, x, rin_in, rin_out, in_spk, f);
      inc = cnt;
      #pragma unroll
      for (int d = 1; d < 64; d <<= 1) {
        int nn = __shfl_up(inc, d, 64);
        if (lane >= d) inc += nn;
      }
      if (lane == 63) wsum[wv] = inc;
    }
    __syncthreads();
    if (tid < 256) {
      int wbase = 0;
      #pragma unroll
      for (int w = 0; w < 4; w++) if (w < wv) wbase += wsum[w];
      int excl = wbase + inc - cnt;
      int o = excl, kb = tid * 4;
      if (f[0]) s_idx[o++] = (unsigned short)(kb);
      if (f[1]) s_idx[o++] = (unsigned short)(kb + 1);
      if (f[2]) s_idx[o++] = (unsigned short)(kb + 2);
      if (f[3]) s_idx[o++] = (unsigned short)(kb + 3);
      if (tid == 0)   s_off[0] = 0;
      if (tid == 96)  s_off[1] = excl;   // panel k=384
      if (tid == 192) s_off[2] = excl;   // panel k=768
      if (tid == 255) s_off[3] = excl + cnt;
    }
    __syncthreads();

    int g  = tid >> 8;                   // 0: panels {0,1}; 1: panel {2}
    int tl = tid & 255;
    int h0 = bx * 1024 + tl * 4;
    const char* Wb = (const char*)W1T;
    unsigned cb = (unsigned)h0 << 2;
    if (g == 0) {
      float t0 = 0.0f, t1 = 0.0f, t2 = 0.0f, t3 = 0.0f;
      #pragma unroll
      for (int p = 0; p < 2; p++) {
        int ks = s_off[p], ke = s_off[p + 1];
        float a0 = 0.0f, a1 = 0.0f, a2 = 0.0f, a3 = 0.0f;
        GATHER8(14)
        t0 = __fadd_rn(t0, a0); t1 = __fadd_rn(t1, a1);   // sA = fadd(fadd(0,P0),P1)
        t2 = __fadd_rn(t2, a2); t3 = __fadd_rn(t3, a3);
      }
      *reinterpret_cast<float4*>(sA + tl * 4) = make_float4(t0, t1, t2, t3);
    } else {
      int ks = s_off[2], ke = s_off[3];
      float a0 = 0.0f, a1 = 0.0f, a2 = 0.0f, a3 = 0.0f;
      GATHER8(14)
      *reinterpret_cast<float4*>(p2 + tl * 4) = make_float4(a0, a1, a2, a3);
    }
    __syncthreads();

    if (tid < 256) {
      float4 sa = *reinterpret_cast<const float4*>(sA + tid * 4);
      float4 pb = *reinterpret_cast<const float4*>(p2 + tid * 4);
      float t0 = __fadd_rn(sa.x, pb.x);  // total = fadd(sA, P2) — exact fold
      float t1 = __fadd_rn(sa.y, pb.y);
      float t2 = __fadd_rn(sa.z, pb.z);
      float t3 = __fadd_rn(sa.w, pb.w);
      size_t idx = (size_t)b * HID + bx * 1024 + tid * 4;
      float4 vv = *reinterpret_cast<float4*>(v_h + idx);
      float4 rr = *reinterpret_cast<float4*>(r_h + idx);
      uchar4 sp;
      sp.x = lif_f32(t0, vv.x, rr.x);
      sp.y = lif_f32(t1, vv.y, rr.y);
      sp.z = lif_f32(t2, vv.z, rr.z);
      sp.w = lif_f32(t3, vv.w, rr.w);
      *reinterpret_cast<float4*>(v_h + idx) = vv;
      *reinterpret_cast<float4*>(r_h + idx) = rr;
      *reinterpret_cast<uchar4*>(hid_spk_w + idx) = sp;
    }
  } else {
    // ---- out role: block covers 256 cols; 11 panels over 8 waves ----
    unsigned short* s_idx = (unsigned short*)smem;              // 8192 B
    int* s_off = (int*)(smem + 8192);                            // 48 B
    int* wsum  = (int*)(smem + 8240);                            // 16 B
    float* parts = (float*)(smem + 8256);                        // 11264 B
    int bx = blockIdx.x - 4;
    unsigned ww[4];
    int cnt = 0, inc = 0;
    if (tid < 256) {
      uint4 u = *reinterpret_cast<const uint4*>(hid_spk_r + (size_t)b * HID + tid * 16);
      ww[0] = u.x; ww[1] = u.y; ww[2] = u.z; ww[3] = u.w;
      #pragma unroll
      for (int j = 0; j < 16; j++) cnt += (ww[j >> 2] >> ((j & 3) * 8)) & 0xff;
      inc = cnt;
      #pragma unroll
      for (int d = 1; d < 64; d <<= 1) {
        int nn = __shfl_up(inc, d, 64);
        if (lane >= d) inc += nn;
      }
      if (lane == 63) wsum[wv] = inc;
    }
    __syncthreads();
    if (tid < 256) {
      int wbase = 0;
      #pragma unroll
      for (int w = 0; w < 4; w++) if (w < wv) wbase += wsum[w];
      int excl = wbase + inc - cnt;
      int oo = excl, kb = tid * 16;
      #pragma unroll
      for (int j = 0; j < 16; j++) {
        if ((ww[j >> 2] >> ((j & 3) * 8)) & 0xff) s_idx[oo++] = (unsigned short)(kb + j);
      }
      if ((tid % 24) == 0 && tid <= 240) s_off[tid / 24] = excl;
      if (tid == 255) s_off[11] = excl + cnt;
    }
    __syncthreads();

    // 11 panels over 8 waves: {0,1},{2,3},{4},{5},{6},{7},{8,9},{10}
    const int pst[8] = {0, 2, 4, 5, 6, 7, 8, 10};
    const int pen[8] = {2, 4, 5, 6, 7, 8, 10, 11};
    int pstart = pst[wv], pend = pen[wv];
    int col0 = lane * 4;
    const char* Wb = (const char*)W2T;
    unsigned cb = ((unsigned)(bx * 256 + col0)) << 2;
    for (int p = pstart; p < pend; p++) {
      int ks = s_off[p], ke = s_off[p + 1];
      float a0 = 0.0f, a1 = 0.0f, a2 = 0.0f, a3 = 0.0f;
      GATHER8(12)
      *reinterpret_cast<float4*>(parts + p * 256 + col0) = make_float4(a0, a1, a2, a3);
    }
    __syncthreads();

    if (tid < 256) {
      float total = 0.0f;
      #pragma unroll
      for (int p = 0; p < 11; p++) total = __fadd_rn(total, parts[p * 256 + tid]);
      int o = bx * 256 + tid;
      size_t idx = (size_t)b * OUTN + o;
      float v = v_o[idx], r = r_o[idx];
      unsigned char fired = lif_f32(total, v, r);
      v_o[idx] = v; r_o[idx] = r;
      if (fired) out_acc[idx] = __fadd_rn(out_acc[idx], 1.0f);
    }
  }
}

// ---------------- STDP: stats1 (counts + flags) then apply2 (trace + W) ----------
#define NWSTAT ((IN + HID) / 4)   // 1280 u32 words
__global__ __launch_bounds__(256) void stats1_k(
    const unsigned char* __restrict__ in_spk, const unsigned char* __restrict__ hid_spk,
    unsigned* __restrict__ pcnt, int* __restrict__ flags) {
  int w = blockIdx.x * 256 + threadIdx.x;   // word index in [0, NWSTAT)
  int r0 = blockIdx.y * 8;                  // 16 chunks x 8 rows
  int lane = threadIdx.x & 63;
  unsigned s = 0;
  if (w < IN / 4) {
    const unsigned* p = (const unsigned*)in_spk;
    #pragma unroll
    for (int b = 0; b < 8; b++) s += p[(size_t)(r0 + b) * (IN / 4) + w];
    atomicAdd(pcnt + w, s);
    unsigned long long any = __ballot(s > 0);
    if (any && lane == 0) atomicOr(flags + 0, 1);
  } else {
    const unsigned* p = (const unsigned*)hid_spk;
    int w2 = w - IN / 4;
    #pragma unroll
    for (int b = 0; b < 8; b++) s += p[(size_t)(r0 + b) * (HID / 4) + w2];
    atomicAdd(pcnt + w, s);
    unsigned long long any = __ballot(s > 0);
    if (any && lane == 0) atomicOr(flags + 1, 1);
  }
}

// apply2: pm = cnt * 2^-7 (== __fdiv_rn(cnt,128), pow2 exact). tp/tn ping-pong
// (read buffer never written -> race-free); W1T update gated by 'both' flags.
__global__ __launch_bounds__(256) void apply2_k(
    float* __restrict__ W1T,
    const unsigned* __restrict__ pcnt,
    const float* __restrict__ tp_in, float* __restrict__ tp_out,
    const float* __restrict__ tn_in, float* __restrict__ tn_out,
    const int* __restrict__ flags) {
  size_t idx = (size_t)blockIdx.x * 256 + threadIdx.x;  // i*HID + h layout
  int i = (int)(idx >> 12);
  int h = (int)(idx & 4095);
  int cnt_i = (int)((pcnt[i >> 2] >> ((i & 3) * 8)) & 0xff);
  int ch = IN + h;
  int cnt_h = (int)((pcnt[ch >> 2] >> ((ch & 3) * 8)) & 0xff);
  float pm_i = __fmul_rn((float)cnt_i, 0.0078125f);     // == fdiv_rn(cnt,128)
  float pm_h = __fmul_rn((float)cnt_h, 0.0078125f);
  float tpn = __fadd_rn(__fmul_rn(0.9f, tp_in[i]), pm_i);
  float tnn = __fadd_rn(__fmul_rn(0.9f, tn_in[h]), pm_h);
  if (h == 0) tp_out[i] = tpn;           // one committer per i
  if (i == 0) tn_out[h] = tnn;           // one committer per h
  if (!(flags[0] && flags[1])) return;   // 'both' gate (W only)
  float a  = __fmul_rn(tpn, pm_h);       // tp_n * post_m
  float b2 = __fmul_rn(pm_i, tnn);       // pre_m * tn_n
  float d  = __fmul_rn(0.001f, __fsub_rn(a, b2));
  float w  = __fadd_rn(W1T[idx], d);
  w = fminf(fmaxf(w, -1.0f), 1.0f);      // jnp.clip: max then min
  W1T[idx] = w;
}

__global__ __launch_bounds__(256) void scale_k(const float* __restrict__ acc,
                                               float* __restrict__ out) {
  int j = blockIdx.x * 256 + threadIdx.x;
  out[j] = __fdiv_rn(acc[j], 100.0f);
}

// ---------------- host launcher ----------------
extern "C" void kernel_launch(void* const* d_in, const int* in_sizes, int n_in,
                              void* d_out, int out_size, void* d_ws, size_t ws_size,
                              hipStream_t stream) {
  (void)in_sizes; (void)n_in; (void)out_size; (void)ws_size;
  const float* x     = (const float*)d_in[0];
  const float* W1    = (const float*)d_in[1];
  const float* W2    = (const float*)d_in[2];
  const float* noise = (const float*)d_in[3];

  char* ws = (char*)d_ws;
  size_t off = 0;
  auto alloc = [&](size_t bytes) -> char* {
    char* p = ws + off;
    off += (bytes + 255) & ~(size_t)255;
    return p;
  };
  float* W1T   = (float*)alloc((size_t)IN * HID * 4);     // 16 MB working copy (i-major)
  float* W2T   = (float*)alloc((size_t)HID * OUTN * 4);   // 16 MB (h-major)
  float* v_h   = (float*)alloc((size_t)BB * HID * 4);
  float* r_h   = (float*)alloc((size_t)BB * HID * 4);
  float* v_o   = (float*)alloc((size_t)BB * OUTN * 4);
  float* r_o   = (float*)alloc((size_t)BB * OUTN * 4);
  float* rinA  = (float*)alloc((size_t)BB * IN * 4);      // ping-pong refractory state
  float* rinB  = (float*)alloc((size_t)BB * IN * 4);
  float* acc   = (float*)alloc((size_t)BB * OUTN * 4);
  float* tpA   = (float*)alloc((size_t)IN * 4);           // ping-pong traces
  float* tpB   = (float*)alloc((size_t)IN * 4);
  float* tnA   = (float*)alloc((size_t)HID * 4);
  float* tnB   = (float*)alloc((size_t)HID * 4);
  unsigned char* in_spk   = (unsigned char*)alloc((size_t)BB * IN);
  unsigned char* hid_spkA = (unsigned char*)alloc((size_t)BB * HID);  // ping-pong
  unsigned char* hid_spkB = (unsigned char*)alloc((size_t)BB * HID);
  unsigned* pcnt = (unsigned*)alloc((size_t)10 * NWSTAT * 4);  // per-STDP-step slots
  int* flags   = (int*)alloc(2 * 10 * sizeof(int));            // per-STDP-step slots

  // zero all state (ws is poisoned before every call)
  hipMemsetAsync(v_h, 0, (size_t)BB * HID * 4, stream);
  hipMemsetAsync(r_h, 0, (size_t)BB * HID * 4, stream);
  hipMemsetAsync(v_o, 0, (size_t)BB * OUTN * 4, stream);
  hipMemsetAsync(r_o, 0, (size_t)BB * OUTN * 4, stream);
  hipMemsetAsync(rinA, 0, (size_t)BB * IN * 4, stream);
  hipMemsetAsync(acc, 0, (size_t)BB * OUTN * 4, stream);
  hipMemsetAsync(tpA, 0, (size_t)IN * 4, stream);
  hipMemsetAsync(tnA, 0, (size_t)HID * 4, stream);
  hipMemsetAsync(pcnt, 0, (size_t)10 * NWSTAT * 4, stream);
  hipMemsetAsync(flags, 0, 2 * 10 * sizeof(int), stream);

  // W1 (HID x IN) -> W1T (IN x HID); W2 (OUTN x HID) -> W2T (HID x OUTN). Tiled.
  ttrans_k<<<dim3(IN / 32, HID / 32), 256, 0, stream>>>(W1, W1T, HID, IN);
  ttrans_k<<<dim3(HID / 32, OUTN / 32), 256, 0, stream>>>(W2, W2T, OUTN, HID);

  float* rin_in = rinA;
  float* rin_out = rinB;
  float* tp_in = tpA; float* tp_out = tpB;
  float* tn_in = tnA; float* tn_out = tnB;

  // t = 0: hidden only
  hidden_k<<<dim3(4, BB), 256, 0, stream>>>(noise, x, rin_in, rin_out, in_spk,
                                            W1T, v_h, r_h, hid_spkA);
  {
    unsigned* pc = pcnt;  int* fl = flags;
    stats1_k<<<dim3(NWSTAT / 256, 16), 256, 0, stream>>>(in_spk, hid_spkA, pc, fl);
    apply2_k<<<(IN * HID) / 256, 256, 0, stream>>>(W1T, pc, tp_in, tp_out,
                                                   tn_in, tn_out, fl);
    float* t1 = tp_in; tp_in = tp_out; tp_out = t1;
    float* t2 = tn_in; tn_in = tn_out; tn_out = t2;
  }
  { float* tmpp = rin_in; rin_in = rin_out; rin_out = tmpp; }

  // t = 1..99: merged out(t-1) || hidden(t), 512-thread blocks
  for (int t = 1; t < TSTEPS; t++) {
    const float* nz = noise + (size_t)t * BB * IN;
    unsigned char* hs_w = (t & 1) ? hid_spkB : hid_spkA;
    unsigned char* hs_r = (t & 1) ? hid_spkA : hid_spkB;
    step_k<<<dim3(8, BB), 512, 0, stream>>>(nz, x, rin_in, rin_out, in_spk,
                                            W1T, v_h, r_h, hs_w, hs_r,
                                            W2T, v_o, r_o, acc);
    if (t % 10 == 0) {
      unsigned* pc = pcnt + (size_t)NWSTAT * (t / 10);
      int* fl = flags + 2 * (t / 10);
      stats1_k<<<dim3(NWSTAT / 256, 16), 256, 0, stream>>>(in_spk, hs_w, pc, fl);
      apply2_k<<<(IN * HID) / 256, 256, 0, stream>>>(W1T, pc, tp_in, tp_out,
                                                     tn_in, tn_out, fl);
      float* t1 = tp_in; tp_in = tp_out; tp_out = t1;
      float* t2 = tn_in; tn_in = tn_out; tn_out = t2;
    }
    float* tmpp = rin_in; rin_in = rin_out; rin_out = tmpp;
  }

  // final: out(99)
  unsigned char* hs_last = ((TSTEPS - 1) & 1) ? hid_spkB : hid_spkA;
  out_k<<<dim3(4, BB), 256, 0, stream>>>(hs_last, W2T, v_o, r_o, acc);

  scale_k<<<(BB * OUTN) / 256, 256, 0, stream>>>(acc, (float*)d_out);
}